// Round 1
// baseline (86.203 us; speedup 1.0000x reference)
//
#include <hip/hip_runtime.h>
#include <hip/hip_bf16.h>

#define IN_F   4096
#define OUT_F  11008
#define BATCH  32
#define NG     32      // K groups of 128
#define PACKS  512     // IN/8 packed ints per output row

typedef __bf16 bf16x8_t __attribute__((ext_vector_type(8)));
typedef float  floatx4_t __attribute__((ext_vector_type(4)));

// ---------------------------------------------------------------------------
// Prep: x fp32 [32,4096] -> bf16, reordered so main-kernel A-fragment loads are
// contiguous 16B/lane. Chunk c (16384 total), 8 elems each:
//   mm=c&31, q=(c>>5)&3, t=(c>>7)&3, g=c>>9
//   xp[c*8+j] = bf16( x[mm][g*128 + q*32 + t*8 + j] )
// This matches the main kernel's virtual k-slot mapping: at (group g, step t),
// lane quad q covers actual k = g*128 + 32q + 8t + j  (same as its B packed int).
// ---------------------------------------------------------------------------
__global__ __launch_bounds__(256) void prep_x(const float* __restrict__ x,
                                              unsigned short* __restrict__ xp) {
  int c  = blockIdx.x * 256 + threadIdx.x;      // 0..16383
  int mm = c & 31;
  int k0 = ((c >> 5) & 3) * 32 + ((c >> 7) & 3) * 8 + (c >> 9) * 128;
  const float* src = x + mm * IN_F + k0;
  float4 f0 = *(const float4*)(src);
  float4 f1 = *(const float4*)(src + 4);
  float v[8] = {f0.x, f0.y, f0.z, f0.w, f1.x, f1.y, f1.z, f1.w};
  union { unsigned short s[8]; uint4 u; } r;
#pragma unroll
  for (int j = 0; j < 8; ++j) {
    unsigned int u = __float_as_uint(v[j]);
    unsigned int rnd = ((u >> 16) & 1u) + 0x7fffu;   // RNE fp32->bf16
    r.s[j] = (unsigned short)((u + rnd) >> 16);
  }
  *(uint4*)(xp + c * 8) = r.u;
}

// signed int4 nibbles (low nibble first) -> 8 exact bf16 values (no scale)
__device__ inline bf16x8_t unpack8(int p) {
  union { unsigned short u[8]; bf16x8_t v; } r;
#pragma unroll
  for (int j = 0; j < 8; ++j) {
    int nib = (p << (28 - 4 * j)) >> 28;             // arithmetic sign-extend
    float f = (float)nib;                            // exact
    r.u[j] = (unsigned short)(__float_as_uint(f) >> 16);  // exact truncation
  }
  return r.v;
}

__device__ inline bf16x8_t load_frag(const unsigned short* p) {
  union { uint4 u; bf16x8_t v; } x;
  x.u = *(const uint4*)p;
  return x.v;
}

// ---------------------------------------------------------------------------
// Main: block = 256 thr (4 waves). Block covers 32 output cols; wave w covers
// K-quarter = groups [w*8, w*8+8). Per group: 2 B dwordx4 loads (native packed
// layout, 64B contiguous per row), 8 A frag loads (16B/lane, coalesced from
// xp), 16 MFMAs into zeroed temps, then fp32 scale into persistent acc.
// Epilogue: LDS reduce over the 4 wave-partials + bias.
// ---------------------------------------------------------------------------
__global__ __launch_bounds__(256) void wql_main(
    const int* __restrict__ pw, const float* __restrict__ scale,
    const float* __restrict__ bias, const unsigned short* __restrict__ xp,
    float* __restrict__ out) {
  __shared__ float lds[4][BATCH * 32];

  const int tid = threadIdx.x;
  const int l   = tid & 63;
  const int w   = tid >> 6;
  const int col = l & 15;
  const int q   = l >> 4;
  const int n0  = blockIdx.x * 32;
  const int nA  = n0 + col;        // n-tile 0 column
  const int nB  = n0 + 16 + col;   // n-tile 1 column

  floatx4_t acc00 = {0.f, 0.f, 0.f, 0.f};
  floatx4_t acc01 = {0.f, 0.f, 0.f, 0.f};
  floatx4_t acc10 = {0.f, 0.f, 0.f, 0.f};
  floatx4_t acc11 = {0.f, 0.f, 0.f, 0.f};

  const int g0 = w * 8;
#pragma unroll 1
  for (int gi = 0; gi < 8; ++gi) {
    const int gg = g0 + gi;
    // B: one dwordx4 per n-tile = 4 packed ints = this lane's 4 step-fragments
    int4 pA = *(const int4*)(pw + nA * PACKS + gg * 16 + q * 4);
    int4 pB = *(const int4*)(pw + nB * PACKS + gg * 16 + q * 4);
    float sA = scale[nA * NG + gg];
    float sB = scale[nB * NG + gg];

    // A: chunk index = gg*512 + t*128 + q*32 + m  (elements *8, bytes *16)
    const unsigned short* ab = xp + (gg * 512 + q * 32 + col) * 8;
    bf16x8_t a0[4], a1[4];
#pragma unroll
    for (int t = 0; t < 4; ++t) {
      a0[t] = load_frag(ab + t * 1024);        // rows 0..15
      a1[t] = load_frag(ab + t * 1024 + 128);  // rows 16..31
    }

    floatx4_t t00 = {0.f, 0.f, 0.f, 0.f};
    floatx4_t t01 = {0.f, 0.f, 0.f, 0.f};
    floatx4_t t10 = {0.f, 0.f, 0.f, 0.f};
    floatx4_t t11 = {0.f, 0.f, 0.f, 0.f};
    int pAv[4] = {pA.x, pA.y, pA.z, pA.w};
    int pBv[4] = {pB.x, pB.y, pB.z, pB.w};
#pragma unroll
    for (int t = 0; t < 4; ++t) {
      bf16x8_t b0 = unpack8(pAv[t]);
      bf16x8_t b1 = unpack8(pBv[t]);
      t00 = __builtin_amdgcn_mfma_f32_16x16x32_bf16(a0[t], b0, t00, 0, 0, 0);
      t10 = __builtin_amdgcn_mfma_f32_16x16x32_bf16(a1[t], b0, t10, 0, 0, 0);
      t01 = __builtin_amdgcn_mfma_f32_16x16x32_bf16(a0[t], b1, t01, 0, 0, 0);
      t11 = __builtin_amdgcn_mfma_f32_16x16x32_bf16(a1[t], b1, t11, 0, 0, 0);
    }
    // group scale (per output column; col == lane&15 == C/D col for all regs)
#pragma unroll
    for (int r = 0; r < 4; ++r) {
      acc00[r] += t00[r] * sA;
      acc10[r] += t10[r] * sA;
      acc01[r] += t01[r] * sB;
      acc11[r] += t11[r] * sB;
    }
  }

  // C/D layout: col = lane&15, row = quad*4 + reg   [verified m89/m91]
#pragma unroll
  for (int r = 0; r < 4; ++r) {
    int row = q * 4 + r;
    lds[w][row * 32 + col]             = acc00[r];
    lds[w][row * 32 + 16 + col]        = acc01[r];
    lds[w][(16 + row) * 32 + col]      = acc10[r];
    lds[w][(16 + row) * 32 + 16 + col] = acc11[r];
  }
  __syncthreads();

  for (int e = tid; e < BATCH * 32; e += 256) {
    int row = e >> 5, cl = e & 31;
    float s = lds[0][e] + lds[1][e] + lds[2][e] + lds[3][e];
    out[row * OUT_F + n0 + cl] = s + bias[n0 + cl];
  }
}

extern "C" void kernel_launch(void* const* d_in, const int* in_sizes, int n_in,
                              void* d_out, int out_size, void* d_ws, size_t ws_size,
                              hipStream_t stream) {
  const float* x     = (const float*)d_in[0];
  const int*   pw    = (const int*)d_in[1];
  const float* scale = (const float*)d_in[2];
  const float* bias  = (const float*)d_in[3];
  float* out = (float*)d_out;
  unsigned short* xp = (unsigned short*)d_ws;   // 256 KiB bf16 staging

  hipLaunchKernelGGL(prep_x, dim3(16384 / 256), dim3(256), 0, stream, x, xp);
  hipLaunchKernelGGL(wql_main, dim3(OUT_F / 32), dim3(256), 0, stream,
                     pw, scale, bias, xp, out);
}